// Round 2
// baseline (108.748 us; speedup 1.0000x reference)
//
#include <hip/hip_runtime.h>
#include <hip/hip_fp16.h>

#define BATCH 16
#define C_IN  64
#define HH    64
#define WW    64
#define COUT  64
#define KK    9
#define HW    4096
#define CK    576
#define MROW  200   // 192 data ushorts + 8 pad; row stride 400 B (16-B aligned)
#define WROWS 13    // staged window rows: [row-6, row+6]
#define WLO   6

typedef _Float16 f16x8 __attribute__((ext_vector_type(8)));
typedef float    f32x4 __attribute__((ext_vector_type(4)));

__device__ __forceinline__ unsigned short f32_to_f16u(float f) {
    _Float16 h = (_Float16)f;       // v_cvt_f16_f32, RNE
    unsigned short u;
    __builtin_memcpy(&u, &h, 2);
    return u;
}

__device__ __forceinline__ __half2 as_h2(unsigned int u) {
    __half2 r; __builtin_memcpy(&r, &u, 4); return r;
}
__device__ __forceinline__ unsigned int as_u32(__half2 v) {
    unsigned int u; __builtin_memcpy(&u, &v, 4); return u;
}

// Fused prep.  Blocks 0..1023: x (B,C,H,W) f32 -> xt (B,H,W,C) f16.
// Blocks 1024..1167: w (Cout,C,3,3) f32 -> wt in MFMA A-fragment order (f16):
//   wt[(((kc*6+ks)*4+ot)*64 + lane)*8 + j] = W[o=ot*16+(lane&15)]
//        [kk=ks*32+(lane>>4)*8+j] of chunk kc  (kk = tap*64+c, k=kc*3+tap)
__global__ __launch_bounds__(256) void prep_kernel(
    const float* __restrict__ x, const float* __restrict__ w,
    unsigned short* __restrict__ xt, unsigned short* __restrict__ wt) {
    __shared__ unsigned short tile[64][72];
    const int t = threadIdx.x;
    const int blk = blockIdx.x;
    if (blk < 1024) {
        const int b = blk >> 6, y = blk & 63;
        const float* xrow = x + ((b * 64) * 64 + y) * 64;
#pragma unroll
        for (int it = 0; it < 4; ++it) {
            const int idx = it * 256 + t;
            const int c = idx >> 4, seg = idx & 15;
            const float4 v = *(const float4*)(xrow + c * HW + seg * 4);
            tile[seg * 4 + 0][c] = f32_to_f16u(v.x);
            tile[seg * 4 + 1][c] = f32_to_f16u(v.y);
            tile[seg * 4 + 2][c] = f32_to_f16u(v.z);
            tile[seg * 4 + 3][c] = f32_to_f16u(v.w);
        }
        __syncthreads();
#pragma unroll
        for (int it = 0; it < 2; ++it) {
            const int idx = it * 256 + t;
            const int xx = idx >> 3, cs = idx & 7;
            *(int4*)&xt[((b * HW) + y * 64 + xx) * 64 + cs * 8] =
                *(const int4*)&tile[xx][cs * 8];
        }
    } else {
        const int i = (blk - 1024) * 256 + t;  // 0..36863
        const int j = i & 7;
        const int l = (i >> 3) & 63;
        const int ot = (i >> 9) & 3;
        const int r = i >> 11;           // 0..17
        const int ks = r % 6, kc = r / 6;
        const int o  = ot * 16 + (l & 15);
        const int kk = ks * 32 + (l >> 4) * 8 + j;
        const int tap = kk >> 6, c = kk & 63;
        const int k = kc * 3 + tap;
        wt[i] = f32_to_f16u(w[o * CK + c * KK + k]);
    }
}

// Main, R9.  Block = 256 thr = 4 waves = ONE output row (64 px) of one batch.
// Theory: R7/R8 were L1-miss-throughput bound on the 302-MB gather stream
// (36x re-read of the 8-MB image through a thrashing 32-KB L1).  Fix: stage
// a 13-row window [row-6,row+6] of xt into LDS once (106.5 KB, async
// global_load_lds) and gather via ds_read_b128.  Offsets are N(0,1):
// P(|z|>=5) ~ 3e-7, so window misses are ~nonexistent, but an exactly-correct
// rare path (flag bit in PWa, __any-guarded global fallback via PWg) handles
// any offset.  This also deletes the in-flight gather register file and the
// vmcnt false-serialization (wt afrag loads are now the only main-loop vmem).
// LDS 150.5 KB -> 1 block/CU, grid 1024 = 4 rounds.
__global__ __launch_bounds__(256, 1) void dcn_main_kernel(
    const float* __restrict__ offset, const float* __restrict__ mask,
    const unsigned short* __restrict__ xt, const unsigned short* __restrict__ wt,
    const float* __restrict__ bias, float* __restrict__ out) {
    __shared__ __align__(16) unsigned short win[WROWS * 64 * 64];  // 106496 B
    __shared__ __align__(16) unsigned short Mlds[4][16 * MROW];    //  25600 B
    __shared__ __align__(16) int PWw[576 * 4];                     //   9216 B
    __shared__ __align__(8) unsigned short PWa[576 * 4];           //   4608 B
    __shared__ __align__(8) unsigned short PWg[576 * 4];           //   4608 B

    const int t    = threadIdx.x;
    const int wave = __builtin_amdgcn_readfirstlane(t >> 6);
    const int lane = t & 63;
    const int quad = lane >> 4, m16 = lane & 15;

    const int blk = blockIdx.x;
    const int xcd = blk & 7;             // L2 image pinning (R2 win)
    const int i7  = blk >> 3;            // 0..127 within XCD
    const int b   = (xcd << 1) | (i7 >> 6);
    const int row = i7 & 63;             // adjacent blocks = adjacent rows:
                                         // 12/13 window rows L2-hot
    const int qbase = wave * 16;

    const float* offb = offset + b * (2 * KK * HW) + row * 64;
    const float* mb   = mask + b * (KK * HW) + row * 64;
    const char* xtb   = (const char*)(xt + b * (HW * 64));

    // ---- Prologue loads first (oldest vmem: counted waits keep staging
    //      in flight while we compute) ----
    float oyv[3], oxv[3], mkv[3];
#pragma unroll
    for (int p = 0; p < 3; ++p) {
        const int it = p * 256 + t;
        if (it < 576) {
            const int tap = it >> 6, q = it & 63;
            oyv[p] = offb[(2 * tap) * HW + q];
            oxv[p] = offb[(2 * tap + 1) * HW + q];
            mkv[p] = mb[tap * HW + q];
        } else { oyv[p] = 0.f; oxv[p] = 0.f; mkv[p] = 0.f; }
    }
    asm volatile("" :: "v"(oyv[0]), "v"(oxv[0]), "v"(mkv[0]),
                       "v"(oyv[1]), "v"(oxv[1]), "v"(mkv[1]),
                       "v"(oyv[2]), "v"(oxv[2]), "v"(mkv[2]));

    // ---- Stage window: 13 rows x 8 KB, async global->LDS, 16 B/lane ----
#pragma unroll
    for (int s = 0; s < 2 * WROWS; ++s) {
        const int slot = s >> 1;
        const int srcrow = min(max(row - WLO + slot, 0), HH - 1);
        const char* src = xtb + srcrow * 8192 + (s & 1) * 4096 + t * 16;
        __builtin_amdgcn_global_load_lds(
            (const __attribute__((address_space(1))) unsigned int*)src,
            (__attribute__((address_space(3))) unsigned int*)
                ((char*)win + s * 4096 + t * 16),
            16, 0, 0);
    }
    __builtin_amdgcn_sched_barrier(0);

    // ---- Prologue compute: params for 576 items (tap 0..8 x q 0..63) ----
#pragma unroll
    for (int p = 0; p < 3; ++p) {
        const int it = p * 256 + t;
        if (it < 576) {
            const int tap = it >> 6, q = it & 63;
            const int ky = (tap * 11) >> 5;      // tap/3 for 0..8
            const int kx = tap - ky * 3;
            const float py  = oyv[p] + (float)(row - 1 + ky);
            const float pxf = oxv[p] + (float)(q - 1 + kx);
            const float y0f = floorf(py), x0f = floorf(pxf);
            const float wy = py - y0f, wx = pxf - x0f;
            const int y0 = (int)y0f, x0 = (int)x0f;
            const int y1 = y0 + 1,   x1 = x0 + 1;
            const float vy0 = (y0 >= 0 && y0 < HH) ? 1.f : 0.f;
            const float vy1 = (y1 >= 0 && y1 < HH) ? 1.f : 0.f;
            const float vx0 = (x0 >= 0 && x0 < WW) ? 1.f : 0.f;
            const float vx1 = (x1 >= 0 && x1 < WW) ? 1.f : 0.f;
            const float mk = mkv[p];
            const float w00 = (1.f - wy) * (1.f - wx) * vy0 * vx0 * mk;
            const float w01 = (1.f - wy) * wx         * vy0 * vx1 * mk;
            const float w10 = wy * (1.f - wx)         * vy1 * vx0 * mk;
            const float w11 = wy * wx                 * vy1 * vx1 * mk;
            const int cy0 = min(max(y0, 0), HH - 1), cy1 = min(max(y1, 0), HH - 1);
            const int cx0 = min(max(x0, 0), WW - 1), cx1 = min(max(x1, 0), WW - 1);
            // window slots (y only; x is always fully staged)
            const int sl0 = cy0 - (row - WLO);
            const int sl1 = cy1 - (row - WLO);
            const int esc = (sl0 < 0) | (sl1 > (WROWS - 1));
            const int c0 = min(max(sl0, 0), WROWS - 1);
            const int c1 = min(max(sl1, 0), WROWS - 1);
            const unsigned int s00 = f32_to_f16u(w00);
            const unsigned int s01 = f32_to_f16u(w01);
            const unsigned int s10 = f32_to_f16u(w10);
            const unsigned int s11 = f32_to_f16u(w11);
            int4 P0;
            P0.x = (int)(s00 | (s00 << 16));   // (w,w) half2 pairs
            P0.y = (int)(s01 | (s01 << 16));
            P0.z = (int)(s10 | (s10 << 16));
            P0.w = (int)(s11 | (s11 << 16));
            *(int4*)&PWw[it * 4] = P0;
            ushort4 A;
            A.x = (unsigned short)((c0 * 64 + cx0) | (esc << 15));
            A.y = (unsigned short)(c0 * 64 + cx1);
            A.z = (unsigned short)(c1 * 64 + cx0);
            A.w = (unsigned short)(c1 * 64 + cx1);
            *(ushort4*)&PWa[it * 4] = A;
            ushort4 G;
            G.x = (unsigned short)(cy0 * 64 + cx0);
            G.y = (unsigned short)(cy0 * 64 + cx1);
            G.z = (unsigned short)(cy1 * 64 + cx0);
            G.w = (unsigned short)(cy1 * 64 + cx1);
            *(ushort4*)&PWg[it * 4] = G;
        }
    }
    __syncthreads();   // staging (vmcnt drained per-wave) + params visible

    f32x4 acc[4];
#pragma unroll
    for (int ot = 0; ot < 4; ++ot)
#pragma unroll
        for (int r = 0; r < 4; ++r) acc[ot][r] = 0.f;

    char* MW = (char*)Mlds[wave];
    const int lg  = lane >> 3;          // pixel-corner subgroup (8 lanes)
    const int co2 = (lane & 7) * 16;    // 16-B channel block within a pixel

#pragma unroll
    for (int kc = 0; kc < 3; ++kc) {
        // ---- gather from LDS window + bilinear combine -> Mlds ----
#pragma unroll
        for (int i = 0; i < 6; ++i) {
            const int l  = i * 8 + lg;                       // item in chunk
            const int it = (3 * kc + (l >> 4)) * 64 + qbase + (l & 15);
            const ushort4 a = *(const ushort4*)&PWa[it * 4]; // broadcast x8
            const int4 p0   = *(const int4*)&PWw[it * 4];    // broadcast x8
            uint4 q0 = *(const uint4*)((const char*)win + (((int)a.x & 0x7FFF) << 7) + co2);
            uint4 q1 = *(const uint4*)((const char*)win + (((int)a.y) << 7) + co2);
            uint4 q2 = *(const uint4*)((const char*)win + (((int)a.z) << 7) + co2);
            uint4 q3 = *(const uint4*)((const char*)win + (((int)a.w) << 7) + co2);
            const bool esc = (a.x & 0x8000u) != 0;
            if (__builtin_expect(__any(esc), 0)) {           // ~never taken
                if (esc) {
                    const ushort4 ga = *(const ushort4*)&PWg[it * 4];
                    q0 = *(const uint4*)(xtb + ((int)ga.x << 7) + co2);
                    q1 = *(const uint4*)(xtb + ((int)ga.y << 7) + co2);
                    q2 = *(const uint4*)(xtb + ((int)ga.z << 7) + co2);
                    q3 = *(const uint4*)(xtb + ((int)ga.w << 7) + co2);
                }
            }
            const __half2 c00 = as_h2((unsigned)p0.x);
            const __half2 c01 = as_h2((unsigned)p0.y);
            const __half2 c10 = as_h2((unsigned)p0.z);
            const __half2 c11 = as_h2((unsigned)p0.w);
            uint4 ov;
            {
                __half2 v = __hmul2(c00, as_h2(q0.x));
                v = __hfma2(c01, as_h2(q1.x), v);
                v = __hfma2(c10, as_h2(q2.x), v);
                v = __hfma2(c11, as_h2(q3.x), v);
                ov.x = as_u32(v);
            }
            {
                __half2 v = __hmul2(c00, as_h2(q0.y));
                v = __hfma2(c01, as_h2(q1.y), v);
                v = __hfma2(c10, as_h2(q2.y), v);
                v = __hfma2(c11, as_h2(q3.y), v);
                ov.y = as_u32(v);
            }
            {
                __half2 v = __hmul2(c00, as_h2(q0.z));
                v = __hfma2(c01, as_h2(q1.z), v);
                v = __hfma2(c10, as_h2(q2.z), v);
                v = __hfma2(c11, as_h2(q3.z), v);
                ov.z = as_u32(v);
            }
            {
                __half2 v = __hmul2(c00, as_h2(q0.w));
                v = __hfma2(c01, as_h2(q1.w), v);
                v = __hfma2(c10, as_h2(q2.w), v);
                v = __hfma2(c11, as_h2(q3.w), v);
                ov.w = as_u32(v);
            }
            *(uint4*)(MW + (l & 15) * 400 + (l >> 4) * 128 + co2) = ov;
        }
        // ---- MFMA phase (wt loads are the only main-loop vmem now) ----
        const unsigned short* wkc = wt + kc * (6 * 4 * 512);
#pragma unroll
        for (int ks = 0; ks < 6; ++ks) {
            const f16x8 bfrag =
                *(const f16x8*)(MW + m16 * 400 + ks * 64 + quad * 16);
#pragma unroll
            for (int ot = 0; ot < 4; ++ot) {
                const f16x8 afrag =
                    *(const f16x8*)(wkc + (ks * 4 + ot) * 512 + lane * 8);
                acc[ot] = __builtin_amdgcn_mfma_f32_16x16x32_f16(afrag, bfrag,
                                                                 acc[ot], 0, 0, 0);
            }
        }
    }

    float* ob = out + b * (COUT * HW) + row * 64 + qbase + m16;
#pragma unroll
    for (int ot = 0; ot < 4; ++ot)
#pragma unroll
        for (int r = 0; r < 4; ++r) {
            const int o = ot * 16 + quad * 4 + r;
            ob[o * HW] = acc[ot][r] + bias[o];
        }
}

extern "C" void kernel_launch(void* const* d_in, const int* in_sizes, int n_in,
                              void* d_out, int out_size, void* d_ws,
                              size_t ws_size, hipStream_t stream) {
    const float* x    = (const float*)d_in[0];
    const float* off  = (const float*)d_in[1];
    const float* mask = (const float*)d_in[2];
    const float* w    = (const float*)d_in[3];
    const float* bias = (const float*)d_in[4];
    float* out = (float*)d_out;

    unsigned short* xt = (unsigned short*)d_ws;                     // 8388608 B
    unsigned short* wt = (unsigned short*)((char*)d_ws + 8388608);  // 73728 B

    prep_kernel<<<1024 + 144, 256, 0, stream>>>(x, w, xt, wt);
    dcn_main_kernel<<<1024, 256, 0, stream>>>(off, mask, xt, wt, bias, out);
}

// Round 3
// 96.751 us; speedup vs baseline: 1.1240x; 1.1240x over previous
//
#include <hip/hip_runtime.h>
#include <hip/hip_fp16.h>

#define BATCH 16
#define C_IN  64
#define HH    64
#define WW    64
#define COUT  64
#define KK    9
#define HW    4096
#define CK    576
#define WROWS 13    // staged window rows: [R-5, R+7] for the row pair R,R+1
#define WLO   5

typedef _Float16 f16x8 __attribute__((ext_vector_type(8)));
typedef float    f32x4 __attribute__((ext_vector_type(4)));

__device__ __forceinline__ unsigned short f32_to_f16u(float f) {
    _Float16 h = (_Float16)f;       // v_cvt_f16_f32, RNE
    unsigned short u;
    __builtin_memcpy(&u, &h, 2);
    return u;
}

__device__ __forceinline__ __half2 as_h2(unsigned int u) {
    __half2 r; __builtin_memcpy(&r, &u, 4); return r;
}
__device__ __forceinline__ unsigned int as_u32(__half2 v) {
    unsigned int u; __builtin_memcpy(&u, &v, 4); return u;
}

// Fused prep.  Blocks 0..1023: x (B,C,H,W) f32 -> xt (B,H,W,C) f16.
// Blocks 1024..1167: w (Cout,C,3,3) f32 -> wt in MFMA A-fragment order (f16):
//   wt[(((kc*6+ks)*4+ot)*64 + lane)*8 + j] = W[o=ot*16+(lane&15)]
//        [kk=ks*32+(lane>>4)*8+j] of chunk kc  (kk = tap*64+c, k=kc*3+tap)
__global__ __launch_bounds__(256) void prep_kernel(
    const float* __restrict__ x, const float* __restrict__ w,
    unsigned short* __restrict__ xt, unsigned short* __restrict__ wt) {
    __shared__ unsigned short tile[64][72];
    const int t = threadIdx.x;
    const int blk = blockIdx.x;
    if (blk < 1024) {
        const int b = blk >> 6, y = blk & 63;
        const float* xrow = x + ((b * 64) * 64 + y) * 64;
#pragma unroll
        for (int it = 0; it < 4; ++it) {
            const int idx = it * 256 + t;
            const int c = idx >> 4, seg = idx & 15;
            const float4 v = *(const float4*)(xrow + c * HW + seg * 4);
            tile[seg * 4 + 0][c] = f32_to_f16u(v.x);
            tile[seg * 4 + 1][c] = f32_to_f16u(v.y);
            tile[seg * 4 + 2][c] = f32_to_f16u(v.z);
            tile[seg * 4 + 3][c] = f32_to_f16u(v.w);
        }
        __syncthreads();
#pragma unroll
        for (int it = 0; it < 2; ++it) {
            const int idx = it * 256 + t;
            const int xx = idx >> 3, cs = idx & 7;
            *(int4*)&xt[((b * HW) + y * 64 + xx) * 64 + cs * 8] =
                *(const int4*)&tile[xx][cs * 8];
        }
    } else {
        const int i = (blk - 1024) * 256 + t;  // 0..36863
        const int j = i & 7;
        const int l = (i >> 3) & 63;
        const int ot = (i >> 9) & 3;
        const int r = i >> 11;           // 0..17
        const int ks = r % 6, kc = r / 6;
        const int o  = ot * 16 + (l & 15);
        const int kk = ks * 32 + (l >> 4) * 8 + j;
        const int tap = kk >> 6, c = kk & 63;
        const int k = kc * 3 + tap;
        wt[i] = f32_to_f16u(w[o * CK + c * KK + k]);
    }
}

// Main, R10.  Block = 512 thr = 8 waves = TWO output rows (2x64 px); grid 512
// = 2 rounds (was 4).  R9 post-mortem: 1 wave/SIMD + 4 serial stage->compute
// rounds + Mlds round-trip ate the LDS-window win (main stayed ~36 us).
// Changes:
//  1. B-fragment built IN-REGISTER: lane (quad,m16) reads exactly the 16 B
//     (8 ch) it needs per corner per k-step via ds_read_b128, combines with
//     pre-packed half2 weights -> bfrag.  Mlds (write+reread) deleted.
//  2. Window XOR-swizzle (s' = s ^ (x&7)), applied on the global SOURCE at
//     global_load_lds staging AND on the read address (both-sides rule):
//     breaks the corner*128 bank alignment (16-way -> ~2-way, free).
//     Swizzle pre-baked into per-corner offsets: 1 v_xor per gather.
//  3. 2 rows share one 13-row window [R-5,R+7]; LDS 140 KB -> 8 waves/CU
//     (2/SIMD), half the staging traffic, half the rounds.
//  4. Escape (|oy|>~4, ~30/tensor): recompute corners + global fallback,
//     exactly correct, ~never taken.
__global__ __launch_bounds__(512, 1) void dcn_main_kernel(
    const float* __restrict__ offset, const float* __restrict__ mask,
    const unsigned short* __restrict__ xt, const unsigned short* __restrict__ wt,
    const float* __restrict__ bias, float* __restrict__ out) {
    __shared__ __align__(16) unsigned short win[WROWS * 4096];   // 106496 B
    __shared__ __align__(16) int PWw[2][576 * 4];                //  18432 B
    __shared__ __align__(16) unsigned int PWa[2][576 * 4];       //  18432 B

    const int t    = threadIdx.x;
    const int wave = __builtin_amdgcn_readfirstlane(t >> 6);
    const int lane = t & 63;
    const int quad = lane >> 4, m16 = lane & 15;
    const int rw   = wave >> 2;          // row within pair
    const int qb   = (wave & 3) * 16;    // px strip base

    const int blk = blockIdx.x;
    const int xcd = blk & 7;             // L2 image pinning (R2 win)
    const int i6  = blk >> 3;            // 0..63 within XCD
    const int b   = (xcd << 1) | (i6 >> 5);
    const int R   = (i6 & 31) * 2;       // even row of the pair
    const int base = R - WLO;            // window first row (may be <0)

    const float* offb = offset + b * (2 * KK * HW);
    const float* mb   = mask + b * (KK * HW);
    const char* xtb   = (const char*)(xt + b * (HW * 64));

    // ---- Prologue loads first (params vmem oldest; staging stays in
    //      flight under the params compute) ----
    float oyv[3], oxv[3], mkv[3];
#pragma unroll
    for (int p = 0; p < 3; ++p) {
        const int it = p * 512 + t;
        if (it < 1152) {
            const int rsel = it >= 576;
            const int j = it - rsel * 576;
            const int tap = j >> 6, q = j & 63;
            const int rowX = R + rsel;
            oyv[p] = offb[(2 * tap) * HW + rowX * 64 + q];
            oxv[p] = offb[(2 * tap + 1) * HW + rowX * 64 + q];
            mkv[p] = mb[tap * HW + rowX * 64 + q];
        } else { oyv[p] = 0.f; oxv[p] = 0.f; mkv[p] = 0.f; }
    }
    asm volatile("" :: "v"(oyv[0]), "v"(oxv[0]), "v"(mkv[0]),
                       "v"(oyv[1]), "v"(oxv[1]), "v"(mkv[1]),
                       "v"(oyv[2]), "v"(oxv[2]), "v"(mkv[2]));

    // ---- Stage window: 13 rows x 8 KB, async global->LDS, swizzled source.
    //      LDS dest linear (HW rule: base + lane*16); global source carries
    //      the inverse swizzle: chan-block s' of pixel pxl holds global
    //      chan-block s' ^ (pxl&7). ----
    const int pxl = t >> 3;
    const int swb = ((t & 7) ^ (pxl & 7)) << 4;
#pragma unroll
    for (int s = 0; s < WROWS; ++s) {
        const int srcrow = min(max(base + s, 0), HH - 1);
        const char* src = xtb + srcrow * 8192 + pxl * 128 + swb;
        __builtin_amdgcn_global_load_lds(
            (const __attribute__((address_space(1))) unsigned int*)src,
            (__attribute__((address_space(3))) unsigned int*)
                ((char*)win + s * 8192 + t * 16),
            16, 0, 0);
    }
    __builtin_amdgcn_sched_barrier(0);

    // ---- Prologue compute: params for 1152 items (row x tap x q) ----
    //      PWa: per-corner pre-swizzled window byte offset
    //           enc(w) = (w<<7) | ((w&7)<<4);  esc flag in bit 31 of .x
#pragma unroll
    for (int p = 0; p < 3; ++p) {
        const int it = p * 512 + t;
        if (it < 1152) {
            const int rsel = it >= 576;
            const int j = it - rsel * 576;
            const int tap = j >> 6, q = j & 63;
            const int rowX = R + rsel;
            const int ky = (tap * 11) >> 5;      // tap/3 for 0..8
            const int kx = tap - ky * 3;
            const float py  = oyv[p] + (float)(rowX - 1 + ky);
            const float pxf = oxv[p] + (float)(q - 1 + kx);
            const float y0f = floorf(py), x0f = floorf(pxf);
            const float wy = py - y0f, wx = pxf - x0f;
            const int y0 = (int)y0f, x0 = (int)x0f;
            const int y1 = y0 + 1,   x1 = x0 + 1;
            const float vy0 = (y0 >= 0 && y0 < HH) ? 1.f : 0.f;
            const float vy1 = (y1 >= 0 && y1 < HH) ? 1.f : 0.f;
            const float vx0 = (x0 >= 0 && x0 < WW) ? 1.f : 0.f;
            const float vx1 = (x1 >= 0 && x1 < WW) ? 1.f : 0.f;
            const float mk = mkv[p];
            const float w00 = (1.f - wy) * (1.f - wx) * vy0 * vx0 * mk;
            const float w01 = (1.f - wy) * wx         * vy0 * vx1 * mk;
            const float w10 = wy * (1.f - wx)         * vy1 * vx0 * mk;
            const float w11 = wy * wx                 * vy1 * vx1 * mk;
            const int cy0 = min(max(y0, 0), HH - 1), cy1 = min(max(y1, 0), HH - 1);
            const int cx0 = min(max(x0, 0), WW - 1), cx1 = min(max(x1, 0), WW - 1);
            const int sl0 = cy0 - base, sl1 = cy1 - base;
            const unsigned esc = (sl0 < 0) | (sl1 > (WROWS - 1));
            const int c0 = min(max(sl0, 0), WROWS - 1);
            const int c1 = min(max(sl1, 0), WROWS - 1);
            const int wl00 = c0 * 64 + cx0, wl01 = c0 * 64 + cx1;
            const int wl10 = c1 * 64 + cx0, wl11 = c1 * 64 + cx1;
            const unsigned int s00 = f32_to_f16u(w00);
            const unsigned int s01 = f32_to_f16u(w01);
            const unsigned int s10 = f32_to_f16u(w10);
            const unsigned int s11 = f32_to_f16u(w11);
            int4 P0;
            P0.x = (int)(s00 | (s00 << 16));   // (w,w) half2 pairs
            P0.y = (int)(s01 | (s01 << 16));
            P0.z = (int)(s10 | (s10 << 16));
            P0.w = (int)(s11 | (s11 << 16));
            *(int4*)&PWw[rsel][j * 4] = P0;
            uint4 A;
            A.x = (unsigned)((wl00 << 7) | ((wl00 & 7) << 4)) | (esc << 31);
            A.y = (unsigned)((wl01 << 7) | ((wl01 & 7) << 4));
            A.z = (unsigned)((wl10 << 7) | ((wl10 & 7) << 4));
            A.w = (unsigned)((wl11 << 7) | ((wl11 & 7) << 4));
            *(uint4*)&PWa[rsel][j * 4] = A;
        }
    }
    __syncthreads();   // staging (per-wave vmcnt) + params visible

    f32x4 acc[4];
#pragma unroll
    for (int ot = 0; ot < 4; ++ot)
#pragma unroll
        for (int r = 0; r < 4; ++r) acc[ot][r] = 0.f;

    const char* winc = (const char*)win;
    const int rowX = R + rw;

#pragma unroll
    for (int kc = 0; kc < 3; ++kc) {
        const unsigned short* wkc = wt + kc * (6 * 4 * 512);
#pragma unroll
        for (int ks = 0; ks < 6; ++ks) {
            const int tap = kc * 3 + (ks >> 1);
            const int it  = tap * 64 + qb + m16;
            const uint4 A  = *(const uint4*)&PWa[rw][it * 4];  // bcast x4
            const int4  p0 = *(const int4*)&PWw[rw][it * 4];   // bcast x4
            const unsigned sswz = (unsigned)(((ks & 1) * 4 + quad) << 4);
            uint4 q0 = *(const uint4*)(winc + ((A.x & 0x7FFFFFFFu) ^ sswz));
            uint4 q1 = *(const uint4*)(winc + (A.y ^ sswz));
            uint4 q2 = *(const uint4*)(winc + (A.z ^ sswz));
            uint4 q3 = *(const uint4*)(winc + (A.w ^ sswz));
            if (__builtin_expect(__any((int)(A.x >> 31)), 0)) {  // ~never
                if (A.x >> 31) {
                    const int q = qb + m16;
                    const int ky = (tap * 11) >> 5;
                    const int kx = tap - ky * 3;
                    const float oy = offb[(2 * tap) * HW + rowX * 64 + q];
                    const float ox = offb[(2 * tap + 1) * HW + rowX * 64 + q];
                    const float py  = oy + (float)(rowX - 1 + ky);
                    const float pxf = ox + (float)(q - 1 + kx);
                    const int y0 = (int)floorf(py), x0 = (int)floorf(pxf);
                    const int cy0 = min(max(y0, 0), HH - 1);
                    const int cy1 = min(max(y0 + 1, 0), HH - 1);
                    const int cx0 = min(max(x0, 0), WW - 1);
                    const int cx1 = min(max(x0 + 1, 0), WW - 1);
                    const int hoff = (ks & 1) * 64 + quad * 16;
                    q0 = *(const uint4*)(xtb + ((cy0 * 64 + cx0) << 7) + hoff);
                    q1 = *(const uint4*)(xtb + ((cy0 * 64 + cx1) << 7) + hoff);
                    q2 = *(const uint4*)(xtb + ((cy1 * 64 + cx0) << 7) + hoff);
                    q3 = *(const uint4*)(xtb + ((cy1 * 64 + cx1) << 7) + hoff);
                }
            }
            const __half2 c00 = as_h2((unsigned)p0.x);
            const __half2 c01 = as_h2((unsigned)p0.y);
            const __half2 c10 = as_h2((unsigned)p0.z);
            const __half2 c11 = as_h2((unsigned)p0.w);
            uint4 ov;
            {
                __half2 v = __hmul2(c00, as_h2(q0.x));
                v = __hfma2(c01, as_h2(q1.x), v);
                v = __hfma2(c10, as_h2(q2.x), v);
                v = __hfma2(c11, as_h2(q3.x), v);
                ov.x = as_u32(v);
            }
            {
                __half2 v = __hmul2(c00, as_h2(q0.y));
                v = __hfma2(c01, as_h2(q1.y), v);
                v = __hfma2(c10, as_h2(q2.y), v);
                v = __hfma2(c11, as_h2(q3.y), v);
                ov.y = as_u32(v);
            }
            {
                __half2 v = __hmul2(c00, as_h2(q0.z));
                v = __hfma2(c01, as_h2(q1.z), v);
                v = __hfma2(c10, as_h2(q2.z), v);
                v = __hfma2(c11, as_h2(q3.z), v);
                ov.z = as_u32(v);
            }
            {
                __half2 v = __hmul2(c00, as_h2(q0.w));
                v = __hfma2(c01, as_h2(q1.w), v);
                v = __hfma2(c10, as_h2(q2.w), v);
                v = __hfma2(c11, as_h2(q3.w), v);
                ov.w = as_u32(v);
            }
            f16x8 bfrag;
            __builtin_memcpy(&bfrag, &ov, 16);
#pragma unroll
            for (int ot = 0; ot < 4; ++ot) {
                const f16x8 afrag =
                    *(const f16x8*)(wkc + (ks * 4 + ot) * 512 + lane * 8);
                acc[ot] = __builtin_amdgcn_mfma_f32_16x16x32_f16(afrag, bfrag,
                                                                 acc[ot], 0, 0, 0);
            }
        }
    }

    float* ob = out + b * (COUT * HW) + rowX * 64 + qb + m16;
#pragma unroll
    for (int ot = 0; ot < 4; ++ot)
#pragma unroll
        for (int r = 0; r < 4; ++r) {
            const int o = ot * 16 + quad * 4 + r;
            ob[o * HW] = acc[ot][r] + bias[o];
        }
}

extern "C" void kernel_launch(void* const* d_in, const int* in_sizes, int n_in,
                              void* d_out, int out_size, void* d_ws,
                              size_t ws_size, hipStream_t stream) {
    const float* x    = (const float*)d_in[0];
    const float* off  = (const float*)d_in[1];
    const float* mask = (const float*)d_in[2];
    const float* w    = (const float*)d_in[3];
    const float* bias = (const float*)d_in[4];
    float* out = (float*)d_out;

    unsigned short* xt = (unsigned short*)d_ws;                     // 8388608 B
    unsigned short* wt = (unsigned short*)((char*)d_ws + 8388608);  // 73728 B

    prep_kernel<<<1024 + 144, 256, 0, stream>>>(x, w, xt, wt);
    dcn_main_kernel<<<512, 512, 0, stream>>>(off, mask, xt, wt, bias, out);
}